// Round 6
// baseline (219.876 us; speedup 1.0000x reference)
//
#include <hip/hip_runtime.h>
#include <stdint.h>

// Problem constants: B=8, S=1024, D=1024, H=16, HD=64
#define BB 8
#define SS 1024
#define DD 1024
#define HH 16
#define HDIM 64

typedef __bf16 bf16x8 __attribute__((ext_vector_type(8)));
typedef float f32x4 __attribute__((ext_vector_type(4)));

__device__ __forceinline__ unsigned short f2bf(float f) {
    union { float f; unsigned u; } v; v.f = f;
    unsigned r = v.u + 0x7fff + ((v.u >> 16) & 1);   // RNE
    return (unsigned short)(r >> 16);
}

__device__ __forceinline__ float exp2fast(float x) {
#if __has_builtin(__builtin_amdgcn_exp2f)
    return __builtin_amdgcn_exp2f(x);
#else
    return __expf(x * 0.69314718f);
#endif
}

// async global->LDS, 16B per lane (LDS dest: wave-uniform base + lane*16)
__device__ __forceinline__ void async16(void* lds, const void* g) {
    __builtin_amdgcn_global_load_lds(
        (const __attribute__((address_space(1))) unsigned int*)g,
        (__attribute__((address_space(3))) unsigned int*)lds, 16, 0, 0);
}

// ================= Kernel 1: prep (unchanged) =================
// blocks 0..4095: X fp32 -> bf16 row-major [8192][1024] (pure streaming)
// blocks 4096..4863: W [K][N] fp32 -> Wt bf16 [N][K] (64x64 LDS transpose tile)
__global__ __launch_bounds__(256) void prep(
    const float* __restrict__ x, unsigned short* __restrict__ xb,
    const float* __restrict__ w0, const float* __restrict__ w1,
    const float* __restrict__ w2,
    unsigned short* __restrict__ f0, unsigned short* __restrict__ f1,
    unsigned short* __restrict__ f2)
{
    int bid = blockIdx.x;
    int tid = threadIdx.x;
    if (bid < 4096) {                       // 4096 * 2048 = 8M floats
        size_t base = ((size_t)bid << 11) + tid * 8;
        float4 v0 = *reinterpret_cast<const float4*>(x + base);
        float4 v1 = *reinterpret_cast<const float4*>(x + base + 4);
        union { unsigned short u16[8]; uint4 v; } o;
        o.u16[0] = f2bf(v0.x); o.u16[1] = f2bf(v0.y);
        o.u16[2] = f2bf(v0.z); o.u16[3] = f2bf(v0.w);
        o.u16[4] = f2bf(v1.x); o.u16[5] = f2bf(v1.y);
        o.u16[6] = f2bf(v1.z); o.u16[7] = f2bf(v1.w);
        *reinterpret_cast<uint4*>(xb + base) = o.v;
        return;
    }
    __shared__ unsigned short tile[64 * 76];
    int idx = bid - 4096;                   // 0..767
    int z = idx >> 8, rem = idx & 255;
    const float* w = (z == 0) ? w0 : (z == 1) ? w1 : w2;
    unsigned short* wf = (z == 0) ? f0 : (z == 1) ? f1 : f2;
    int kt = rem & 15, nt = rem >> 4;
    const float* src = w + (size_t)(kt * 64) * DD + nt * 64;
    #pragma unroll
    for (int i = 0; i < 4; ++i) {
        int f = tid + i * 256;
        int r = f >> 4, c4 = f & 15;        // r = k (local), c4 = n/4 (local)
        float4 v = *reinterpret_cast<const float4*>(src + r * DD + c4 * 4);
        ushort4 o;
        o.x = f2bf(v.x); o.y = f2bf(v.y); o.z = f2bf(v.z); o.w = f2bf(v.w);
        *reinterpret_cast<ushort4*>(&tile[r * 76 + c4 * 4]) = o;
    }
    __syncthreads();
    // write transposed: Wt[n0+r][k0 + c8*8 .. +7]
    #pragma unroll
    for (int i = 0; i < 2; ++i) {
        int s = tid + i * 256;
        int r = s >> 3, c8 = s & 7;
        unsigned short tmp[8];
        #pragma unroll
        for (int j = 0; j < 8; ++j) tmp[j] = tile[(c8 * 8 + j) * 76 + r];
        *reinterpret_cast<uint4*>(wf + (size_t)(nt * 64 + r) * DD + kt * 64 + c8 * 8) =
            *reinterpret_cast<const uint4*>(tmp);
    }
}

// ================= Kernel 2: fused QKV GEMM v6 — BK=32, pair-rotation swizzle =================
// 128x128 tile, BK=32, 3 blocks/CU (12 waves/CU, m97 regime). A row is 64B =
// HALF a bank-row, so span index = (row*4 + chunk) mod 8: rotating the chunk
// by (row>>1) (not row!) makes (parity, chunk) cover all 8 16B-spans twice
// per quarter-wave -> 2-way (free). Round-5's row-rotation collapsed to 4 of
// 8 spans = 4-way (6.29M conflicts). Counted vmcnt(4); 1536 blocks = 2 exact
// rounds at 3/CU.
__global__ __launch_bounds__(256, 3) void gemm_qkv(
    const unsigned short* __restrict__ xb,
    const unsigned short* __restrict__ wt0, const unsigned short* __restrict__ wt1,
    const unsigned short* __restrict__ wt2,
    const float* __restrict__ b0, const float* __restrict__ b1, const float* __restrict__ b2,
    unsigned short* __restrict__ qo, unsigned short* __restrict__ ko,
    unsigned short* __restrict__ vto)
{
    // K-loop uses [0..16384): A0|A1|B0|B1, 4096 shorts (8KB) each.
    // Epilogue staging needs 4*4864 = 19456 shorts (38912 B total).
    __shared__ unsigned short SH[19456];

    int bid = blockIdx.x;
    int xcd = bid & 7, g = bid >> 3;        // g 0..191
    int strip = xcd * 3 + (g % 3);          // 0..23
    int mt = g / 3;                         // 0..63
    int nt = strip & 7, z = strip >> 3;

    const unsigned short* wt; const float* bias; unsigned short* out;
    if (z == 0)      { wt = wt0; bias = b0; out = qo; }
    else if (z == 1) { wt = wt1; bias = b1; out = ko; }
    else             { wt = wt2; bias = b2; out = vto; }

    int tid = threadIdx.x;
    int wave = tid >> 6, lane = tid & 63, lq = lane >> 4, lm = lane & 15;
    int wr = wave >> 1, wc = wave & 1;

    // staging: 128 rows x 32 cols = 512 chunks of 16B per buffer; thread
    // covers chunks o = tid, tid+256. Linear LDS dest, inverse-swizzled
    // global src: logical chunk cl = (cs - (rw>>1)) & 3 lands at slot cs.
    const unsigned short* sA[2]; const unsigned short* sB[2];
    int dOff[2];
    #pragma unroll
    for (int s = 0; s < 2; ++s) {
        int o = tid + s * 256;
        int rw = o >> 2, cs = o & 3;
        int cl = (cs - (rw >> 1)) & 3;      // PAIR rotation (row>>1)
        dOff[s] = o * 8;
        sA[s] = xb + (size_t)(mt * 128 + rw) * DD + cl * 8;
        sB[s] = wt + (size_t)(nt * 128 + rw) * DD + cl * 8;
    }

#define STAGE(P, KT)                                                          \
    {                                                                         \
        _Pragma("unroll") for (int s_ = 0; s_ < 2; ++s_)                      \
            async16(&SH[(P) * 4096 + dOff[s_]], sA[s_] + (KT) * 32);          \
        _Pragma("unroll") for (int s_ = 0; s_ < 2; ++s_)                      \
            async16(&SH[8192 + (P) * 4096 + dOff[s_]], sB[s_] + (KT) * 32);   \
    }

    // fragment read offsets (shorts): row*32 + swizzled_chunk*8,
    // chunk = (lq + (row>>1)) & 3  — matches the staging involution.
    int rA[4], rB[4];
    #pragma unroll
    for (int i = 0; i < 4; ++i) {
        int rwA = wr * 64 + i * 16 + lm;
        int rwB = wc * 64 + i * 16 + lm;
        rA[i] = rwA * 32 + ((lq + (rwA >> 1)) & 3) * 8;
        rB[i] = rwB * 32 + ((lq + (rwB >> 1)) & 3) * 8;
    }

    f32x4 acc[4][4] = {};

#define COMPUTE(P)                                                            \
    {                                                                         \
        const unsigned short* Abuf = &SH[(P) * 4096];                         \
        const unsigned short* Bbuf = &SH[8192 + (P) * 4096];                  \
        bf16x8 af[4], bf[4];                                                  \
        _Pragma("unroll") for (int i_ = 0; i_ < 4; ++i_)                      \
            af[i_] = *reinterpret_cast<const bf16x8*>(Abuf + rA[i_]);         \
        _Pragma("unroll") for (int j_ = 0; j_ < 4; ++j_)                      \
            bf[j_] = *reinterpret_cast<const bf16x8*>(Bbuf + rB[j_]);         \
        _Pragma("unroll") for (int i_ = 0; i_ < 4; ++i_)                      \
            _Pragma("unroll") for (int j_ = 0; j_ < 4; ++j_)                  \
                acc[i_][j_] = __builtin_amdgcn_mfma_f32_16x16x32_bf16(        \
                    af[i_], bf[j_], acc[i_][j_], 0, 0, 0);                    \
    }

    STAGE(0, 0);
    STAGE(1, 1);                            // 8 loads in flight

    for (int kt = 0; kt < 30; ++kt) {
        int p = kt & 1;
        // retire tile kt's 4 loads; tile kt+1's 4 stay in flight
        asm volatile("s_waitcnt vmcnt(4)" ::: "memory");
        __builtin_amdgcn_s_barrier();       // tile kt fully in LDS
        __builtin_amdgcn_sched_barrier(0);
        COMPUTE(p);
        asm volatile("s_waitcnt lgkmcnt(0)" ::: "memory");  // reads of buf p done
        __builtin_amdgcn_sched_barrier(0);
        __builtin_amdgcn_s_barrier();       // all waves done reading buf p
        STAGE(p, kt + 2);                   // overwrite buf p with tile kt+2
    }
    // kt = 30
    asm volatile("s_waitcnt vmcnt(4)" ::: "memory");
    __builtin_amdgcn_s_barrier();
    __builtin_amdgcn_sched_barrier(0);
    COMPUTE(0);
    // kt = 31
    asm volatile("s_waitcnt vmcnt(0)" ::: "memory");
    __builtin_amdgcn_s_barrier();
    __builtin_amdgcn_sched_barrier(0);
    COMPUTE(1);
#undef STAGE
#undef COMPUTE

    __syncthreads();                        // before epilogue reuses SH as staging

    // ---------------- epilogue (identical layout) ----------------
    int m0 = mt * 128;
    int col0 = nt * 128 + wc * 64;          // wave's 64-col block = one head
    if (z == 2) {
        #pragma unroll
        for (int j = 0; j < 4; ++j) {
            int col = col0 + j * 16 + lm;
            float bsv = bias[col];
            int h = col >> 6, hd = col & 63;
            #pragma unroll
            for (int i = 0; i < 4; ++i) {
                int m = m0 + wr * 64 + i * 16 + lq * 4;
                int b_ = m >> 10, sr = m & 1023;
                union { float f; unsigned u; } p0, p1, p2, p3;
                p0.f = acc[i][j][0] + bsv; p1.f = acc[i][j][1] + bsv;
                p2.f = acc[i][j][2] + bsv; p3.f = acc[i][j][3] + bsv;
                uint2 pk;
                pk.x = __builtin_amdgcn_perm(p1.u + 0x8000u, p0.u + 0x8000u, 0x07060302u);
                pk.y = __builtin_amdgcn_perm(p3.u + 0x8000u, p2.u + 0x8000u, 0x07060302u);
                *reinterpret_cast<uint2*>(out + (((b_ * HH + h) * HDIM + hd) << 10) + sr) = pk;
            }
        }
    } else {
        unsigned short* S = SH + wave * 4864;   // 64*76 per wave
        #pragma unroll
        for (int j = 0; j < 4; ++j) {
            float bsv = bias[col0 + j * 16 + lm];
            #pragma unroll
            for (int i = 0; i < 4; ++i) {
                #pragma unroll
                for (int r = 0; r < 4; ++r) {
                    union { float f; unsigned u; } cv; cv.f = acc[i][j][r] + bsv;
                    S[(i * 16 + lq * 4 + r) * 76 + j * 16 + lm] =
                        (unsigned short)((cv.u + 0x8000u) >> 16);
                }
            }
        }
        int h = col0 >> 6;
        int mrow = m0 + wr * 64;
        int b_ = mrow >> 10, sr0 = mrow & 1023;
        unsigned short* ob = out + ((size_t)((b_ * HH + h) << 10) + sr0) * HDIM;
        #pragma unroll
        for (int u = 0; u < 8; ++u) {
            int s = lane + u * 64;
            int row = s >> 3, c8 = s & 7;
            uint4 v = *reinterpret_cast<const uint4*>(&S[row * 76 + c8 * 8]);
            *reinterpret_cast<uint4*>(ob + row * HDIM + c8 * 8) = v;
        }
    }
}

// ================= Kernel 3: flash attention v7 (unchanged) =================
// 256 q-rows/block (4 strips of 16 per wave, 64 apart), Kt=64, 16 iters.
// One kf/vf LDS read pair feeds FOUR strips' MFMAs. 512 blocks, 2 blocks/CU.
__global__ __launch_bounds__(256, 2) void attention(
    const unsigned short* __restrict__ q,     // [bh][s][hd]
    const unsigned short* __restrict__ k,     // [bh][s][hd]
    const unsigned short* __restrict__ vt,    // [bh][hd][s]
    const float* __restrict__ mask,
    float* __restrict__ out)
{
    __shared__ unsigned short Ks[2][64 * 64];   // [key][hd], swizzled chunks
    __shared__ unsigned short Vs[2][64 * 64];   // [hd][key], swizzled chunks
    __shared__ unsigned short Ps[4][16 * 64];   // per-wave P[q][key], swizzled

    int blk = blockIdx.x;
    int xcd = blk & 7, j = blk >> 3;            // j 0..63
    int bh = (xcd << 4) + (j >> 2);
    int qt = j & 3;                             // 0..3: 256 q-rows each
    int b = bh >> 4, h = bh & 15;

    int tid = threadIdx.x;
    int wave = tid >> 6, lane = tid & 63, lq = lane >> 4, lm = lane & 15;

    const unsigned short* qp = q + (size_t)bh * SS * HDIM;
    const unsigned short* kp = k + (size_t)bh * SS * HDIM;
    const unsigned short* vp = vt + (size_t)bh * HDIM * SS;
    const float* maskb = mask + b * SS;

    // Q fragments for 4 strips (B-operand: B[k=lq*8+j][n=lm])
    int qbase = qt * 256 + wave * 16 + lm;
    bf16x8 qa[4][2];
    #pragma unroll
    for (int s = 0; s < 4; ++s) {
        qa[s][0] = *reinterpret_cast<const bf16x8*>(qp + (qbase + s * 64) * HDIM + lq * 8);
        qa[s][1] = *reinterpret_cast<const bf16x8*>(qp + (qbase + s * 64) * HDIM + 32 + lq * 8);
    }

    float lsum[4] = {0.f, 0.f, 0.f, 0.f};
    f32x4 o[4][4] = {};                         // [strip][nb2]

    // staging: slot tid -> (row=tid>>3, s=tid&7); +256 -> row+32
    int row0 = tid >> 3, sg = tid & 7;
    int cg = (sg - row0) & 7;                   // chunk swizzle (c + row) & 7
    const unsigned short* gk = kp + row0 * 64 + cg * 8;
    const unsigned short* gv = vp + row0 * SS + cg * 8;

    int sl0 = ((lq + lm) & 7) * 8;              // Ks/Vs frag swizzled offsets
    int sl1 = ((lq + lm + 4) & 7) * 8;
    unsigned short* Pw = Ps[wave];
    int pwbase = lm * 64 + (lq & 1) * 4;        // P-write: chunk nb*2+(lq>>1)
    int prd0 = lm * 64 + sl0;                   // P-read chunk lq (ks=0)
    int prd1 = lm * 64 + sl1;                   // P-read chunk 4+lq (ks=1)

    async16(&Ks[0][tid * 8], gk);  async16(&Ks[0][(tid + 256) * 8], gk + 32 * 64);
    async16(&Vs[0][tid * 8], gv);  async16(&Vs[0][(tid + 256) * 8], gv + 32 * SS);
    gk += 64 * 64; gv += 64;

    for (int t = 0; t < 16; ++t) {
        int p = t & 1;
        __syncthreads();
        int kb0 = t * 64;

        // mask (L2-hot) BEFORE prefetch: its vmcnt wait tolerates the asyncs
        float4 mk[4];
        #pragma unroll
        for (int nb = 0; nb < 4; ++nb) {
            mk[nb] = *reinterpret_cast<const float4*>(maskb + kb0 + nb * 16 + lq * 4);
            #pragma unroll
            for (int r = 0; r < 4; ++r)
                reinterpret_cast<float*>(&mk[nb])[r] *= 1.44269504f;
        }
        if (t < 15) {
            async16(&Ks[p ^ 1][tid * 8], gk);  async16(&Ks[p ^ 1][(tid + 256) * 8], gk + 32 * 64);
            async16(&Vs[p ^ 1][tid * 8], gv);  async16(&Vs[p ^ 1][(tid + 256) * 8], gv + 32 * SS);
            gk += 64 * 64; gv += 64;
        }

        // 1. scores for ALL 4 strips off one Ks read pair per nb
        f32x4 c[4][4];                          // [strip][nb]
        #pragma unroll
        for (int nb = 0; nb < 4; ++nb) {
            bf16x8 kf0 = *reinterpret_cast<const bf16x8*>(&Ks[p][(nb * 16 + lm) * 64 + sl0]);
            bf16x8 kf1 = *reinterpret_cast<const bf16x8*>(&Ks[p][(nb * 16 + lm) * 64 + sl1]);
            #pragma unroll
            for (int s = 0; s < 4; ++s) {
                f32x4 z = {};
                z = __builtin_amdgcn_mfma_f32_16x16x32_bf16(kf0, qa[s][0], z, 0, 0, 0);
                z = __builtin_amdgcn_mfma_f32_16x16x32_bf16(kf1, qa[s][1], z, 0, 0, 0);
                c[s][nb] = z;
            }
        }

        // 2. per strip: exp + P-write + P-read (in-order DS reuse of Ps, x4)
        bf16x8 pa[4][2];
        #pragma unroll
        for (int s = 0; s < 4; ++s) {
            #pragma unroll
            for (int nb = 0; nb < 4; ++nb) {
                unsigned u[4];
                #pragma unroll
                for (int r = 0; r < 4; ++r) {
                    float e = exp2fast(fmaf(c[s][nb][r], 0.18033688f,
                                            reinterpret_cast<const float*>(&mk[nb])[r]));
                    union { float f; unsigned v; } cv; cv.f = e;
                    u[r] = cv.v;
                    union { unsigned v; float f; } tr; tr.v = cv.v & 0xffff0000u;
                    lsum[s] += tr.f;            // lsum of TRUNCATED p: exact cancel
                }
                uint2 pk;
                pk.x = __builtin_amdgcn_perm(u[1], u[0], 0x07060302u);
                pk.y = __builtin_amdgcn_perm(u[3], u[2], 0x07060302u);
                *reinterpret_cast<uint2*>(
                    &Pw[pwbase + (((nb * 2 + (lq >> 1)) + lm) & 7) * 8]) = pk;
            }
            pa[s][0] = *reinterpret_cast<const bf16x8*>(&Pw[prd0]);
            pa[s][1] = *reinterpret_cast<const bf16x8*>(&Pw[prd1]);
        }

        // 3. PV: each Vs read pair feeds all 4 strips
        #pragma unroll
        for (int nb2 = 0; nb2 < 4; ++nb2) {
            bf16x8 vf0 = *reinterpret_cast<const bf16x8*>(&Vs[p][(nb2 * 16 + lm) * 64 + sl0]);
            bf16x8 vf1 = *reinterpret_cast<const bf16x8*>(&Vs[p][(nb2 * 16 + lm) * 64 + sl1]);
            #pragma unroll
            for (int s = 0; s < 4; ++s) {
                o[s][nb2] = __builtin_amdgcn_mfma_f32_16x16x32_bf16(pa[s][0], vf0, o[s][nb2], 0, 0, 0);
                o[s][nb2] = __builtin_amdgcn_mfma_f32_16x16x32_bf16(pa[s][1], vf1, o[s][nb2], 0, 0, 0);
            }
        }
    }

    // reduce lsum (per qrow=lm, 4 lq-copies) and write all 4 strips
    float linv[4][4];
    #pragma unroll
    for (int s = 0; s < 4; ++s) {
        lsum[s] += __shfl_xor(lsum[s], 16, 64);
        lsum[s] += __shfl_xor(lsum[s], 32, 64);
        #pragma unroll
        for (int r = 0; r < 4; ++r)
            linv[s][r] = 1.0f / __shfl(lsum[s], lq * 4 + r, 64);
    }

    int srb = qt * 256 + wave * 16;
    #pragma unroll
    for (int s = 0; s < 4; ++s) {
        #pragma unroll
        for (int nb2 = 0; nb2 < 4; ++nb2) {
            #pragma unroll
            for (int r = 0; r < 4; ++r) {
                int sr = srb + s * 64 + lq * 4 + r;
                out[((size_t)(b * SS + sr)) * DD + h * HDIM + nb2 * 16 + lm] =
                    o[s][nb2][r] * linv[s][r];
            }
        }
    }
}

extern "C" void kernel_launch(void* const* d_in, const int* in_sizes, int n_in,
                              void* d_out, int out_size, void* d_ws, size_t ws_size,
                              hipStream_t stream) {
    const float* hs   = (const float*)d_in[0];
    const float* mask = (const float*)d_in[1];
    const float* Wq   = (const float*)d_in[2];
    const float* bq   = (const float*)d_in[3];
    const float* Wk   = (const float*)d_in[4];
    const float* bk   = (const float*)d_in[5];
    const float* Wv   = (const float*)d_in[6];
    const float* bv   = (const float*)d_in[7];
    float* out = (float*)d_out;

    char* ws = (char*)d_ws;
    // ws layout (bytes): Xb 16MB | Wt0/1/2 2MB each | q,k,vt 16MB each = 70MB
    unsigned short* XB  = (unsigned short*)(ws);
    unsigned short* WT0 = (unsigned short*)(ws + 16777216);
    unsigned short* WT1 = (unsigned short*)(ws + 18874368);
    unsigned short* WT2 = (unsigned short*)(ws + 20971520);
    unsigned short* qw  = (unsigned short*)(ws + 23068672);
    unsigned short* kw  = (unsigned short*)(ws + 39845888);
    unsigned short* vtw = (unsigned short*)(ws + 56623104);

    prep<<<4864, 256, 0, stream>>>(hs, XB, Wq, Wk, Wv, WT0, WT1, WT2);
    gemm_qkv<<<1536, 256, 0, stream>>>(XB, WT0, WT1, WT2,
                                       bq, bk, bv, qw, kw, vtw);
    attention<<<512, 256, 0, stream>>>(qw, kw, vtw, mask, out);
}

// Round 7
// 208.454 us; speedup vs baseline: 1.0548x; 1.0548x over previous
//
#include <hip/hip_runtime.h>
#include <stdint.h>

// Problem constants: B=8, S=1024, D=1024, H=16, HD=64
#define BB 8
#define SS 1024
#define DD 1024
#define HH 16
#define HDIM 64

typedef __bf16 bf16x8 __attribute__((ext_vector_type(8)));
typedef float f32x4 __attribute__((ext_vector_type(4)));

__device__ __forceinline__ unsigned short f2bf(float f) {
    union { float f; unsigned u; } v; v.f = f;
    unsigned r = v.u + 0x7fff + ((v.u >> 16) & 1);   // RNE
    return (unsigned short)(r >> 16);
}

__device__ __forceinline__ float exp2fast(float x) {
#if __has_builtin(__builtin_amdgcn_exp2f)
    return __builtin_amdgcn_exp2f(x);
#else
    return __expf(x * 0.69314718f);
#endif
}

// async global->LDS, 16B per lane (LDS dest: wave-uniform base + lane*16)
__device__ __forceinline__ void async16(void* lds, const void* g) {
    __builtin_amdgcn_global_load_lds(
        (const __attribute__((address_space(1))) unsigned int*)g,
        (__attribute__((address_space(3))) unsigned int*)lds, 16, 0, 0);
}

// ================= Kernel 1: prep =================
// blocks 0..4095: X fp32 -> bf16 row-major [8192][1024] (pure streaming)
// blocks 4096..4863: W [K][N] fp32 -> Wt bf16 [N][K] (64x64 LDS transpose tile)
__global__ __launch_bounds__(256) void prep(
    const float* __restrict__ x, unsigned short* __restrict__ xb,
    const float* __restrict__ w0, const float* __restrict__ w1,
    const float* __restrict__ w2,
    unsigned short* __restrict__ f0, unsigned short* __restrict__ f1,
    unsigned short* __restrict__ f2)
{
    int bid = blockIdx.x;
    int tid = threadIdx.x;
    if (bid < 4096) {                       // 4096 * 2048 = 8M floats
        size_t base = ((size_t)bid << 11) + tid * 8;
        float4 v0 = *reinterpret_cast<const float4*>(x + base);
        float4 v1 = *reinterpret_cast<const float4*>(x + base + 4);
        union { unsigned short u16[8]; uint4 v; } o;
        o.u16[0] = f2bf(v0.x); o.u16[1] = f2bf(v0.y);
        o.u16[2] = f2bf(v0.z); o.u16[3] = f2bf(v0.w);
        o.u16[4] = f2bf(v1.x); o.u16[5] = f2bf(v1.y);
        o.u16[6] = f2bf(v1.z); o.u16[7] = f2bf(v1.w);
        *reinterpret_cast<uint4*>(xb + base) = o.v;
        return;
    }
    __shared__ unsigned short tile[64 * 76];
    int idx = bid - 4096;                   // 0..767
    int z = idx >> 8, rem = idx & 255;
    const float* w = (z == 0) ? w0 : (z == 1) ? w1 : w2;
    unsigned short* wf = (z == 0) ? f0 : (z == 1) ? f1 : f2;
    int kt = rem & 15, nt = rem >> 4;
    const float* src = w + (size_t)(kt * 64) * DD + nt * 64;
    #pragma unroll
    for (int i = 0; i < 4; ++i) {
        int f = tid + i * 256;
        int r = f >> 4, c4 = f & 15;        // r = k (local), c4 = n/4 (local)
        float4 v = *reinterpret_cast<const float4*>(src + r * DD + c4 * 4);
        ushort4 o;
        o.x = f2bf(v.x); o.y = f2bf(v.y); o.z = f2bf(v.z); o.w = f2bf(v.w);
        *reinterpret_cast<ushort4*>(&tile[r * 76 + c4 * 4]) = o;
    }
    __syncthreads();
    // write transposed: Wt[n0+r][k0 + c8*8 .. +7]
    #pragma unroll
    for (int i = 0; i < 2; ++i) {
        int s = tid + i * 256;
        int r = s >> 3, c8 = s & 7;
        unsigned short tmp[8];
        #pragma unroll
        for (int j = 0; j < 8; ++j) tmp[j] = tile[(c8 * 8 + j) * 76 + r];
        *reinterpret_cast<uint4*>(wf + (size_t)(nt * 64 + r) * DD + kt * 64 + c8 * 8) =
            *reinterpret_cast<const uint4*>(tmp);
    }
}

// ================= Kernel 2: fused QKV GEMM (verified best: 63.5us, 811 TF) =================
// 128x128 tile, BK=64, LDS double-buffered via global_load_lds (16B),
// rotation-swizzled 16B chunks ((c+row)&7) -> 2-way (free) ds_read_b128,
// counted vmcnt(8) + raw s_barrier: next tile's 8 loads stay in flight,
// never drained to 0 in the main loop. LDS 64KB -> 2 blocks/CU.
// 1536 blocks = 6 exact CU rounds (packing 100%).
// NOTE (session ledger): BK=32@3blk/CU null even with 0 conflicts (r6);
// 8-phase 256^2-family ports lose to 1.5-round packing (r2,r3); this
// structure is LDS-read-pipe-bound (~2048 LDS-cyc vs 1242 MFMA-cyc per
// 2 block-tiles/CU) and per-wave-tile growth is VGPR-infeasible.
__global__ __launch_bounds__(256, 2) void gemm_qkv(
    const unsigned short* __restrict__ xb,
    const unsigned short* __restrict__ wt0, const unsigned short* __restrict__ wt1,
    const unsigned short* __restrict__ wt2,
    const float* __restrict__ b0, const float* __restrict__ b1, const float* __restrict__ b2,
    unsigned short* __restrict__ qo, unsigned short* __restrict__ ko,
    unsigned short* __restrict__ vto)
{
    __shared__ unsigned short SH[32768];    // 64KB: A0|A1|B0|B1, 8192 shorts each

    int bid = blockIdx.x;
    int xcd = bid & 7, g = bid >> 3;        // g 0..191
    int strip = xcd * 3 + (g % 3);          // 0..23
    int mt = g / 3;                         // 0..63
    int nt = strip & 7, z = strip >> 3;

    const unsigned short* wt; const float* bias; unsigned short* out;
    if (z == 0)      { wt = wt0; bias = b0; out = qo; }
    else if (z == 1) { wt = wt1; bias = b1; out = ko; }
    else             { wt = wt2; bias = b2; out = vto; }

    int tid = threadIdx.x;
    int wave = tid >> 6, lane = tid & 63, lq = lane >> 4, lm = lane & 15;
    int wr = wave >> 1, wc = wave & 1;

    // staging: linear LDS dest (chunk o = tid + s*256), inverse-swizzled global src
    const unsigned short* sA[4]; const unsigned short* sB[4];
    int dOff[4];
    #pragma unroll
    for (int s = 0; s < 4; ++s) {
        int o = tid + s * 256;
        int rw = o >> 3, cs = o & 7;
        int cl = (cs - rw) & 7;             // logical chunk that lands at (rw, cs)
        dOff[s] = o * 8;
        sA[s] = xb + (size_t)(mt * 128 + rw) * DD + cl * 8;
        sB[s] = wt + (size_t)(nt * 128 + rw) * DD + cl * 8;
    }

#define STAGE(P, KT)                                                          \
    {                                                                         \
        _Pragma("unroll") for (int s_ = 0; s_ < 4; ++s_)                      \
            async16(&SH[(P) * 8192 + dOff[s_]], sA[s_] + (KT) * 64);          \
        _Pragma("unroll") for (int s_ = 0; s_ < 4; ++s_)                      \
            async16(&SH[16384 + (P) * 8192 + dOff[s_]], sB[s_] + (KT) * 64);  \
    }

    // fragment read offsets (shorts): row*64 + swizzled_chunk*8
    int rA[4][2], rB[4][2];
    #pragma unroll
    for (int i = 0; i < 4; ++i) {
        int rwA = wr * 64 + i * 16 + lm;
        int rwB = wc * 64 + i * 16 + lm;
        #pragma unroll
        for (int ks = 0; ks < 2; ++ks) {
            rA[i][ks] = rwA * 64 + (((ks * 4 + lq) + rwA) & 7) * 8;
            rB[i][ks] = rwB * 64 + (((ks * 4 + lq) + rwB) & 7) * 8;
        }
    }

    f32x4 acc[4][4] = {};

#define COMPUTE(P)                                                            \
    {                                                                         \
        const unsigned short* Abuf = &SH[(P) * 8192];                         \
        const unsigned short* Bbuf = &SH[16384 + (P) * 8192];                 \
        _Pragma("unroll") for (int ks_ = 0; ks_ < 2; ++ks_) {                 \
            bf16x8 af[4], bf[4];                                              \
            _Pragma("unroll") for (int i_ = 0; i_ < 4; ++i_)                  \
                af[i_] = *reinterpret_cast<const bf16x8*>(Abuf + rA[i_][ks_]);\
            _Pragma("unroll") for (int j_ = 0; j_ < 4; ++j_)                  \
                bf[j_] = *reinterpret_cast<const bf16x8*>(Bbuf + rB[j_][ks_]);\
            _Pragma("unroll") for (int i_ = 0; i_ < 4; ++i_)                  \
                _Pragma("unroll") for (int j_ = 0; j_ < 4; ++j_)              \
                    acc[i_][j_] = __builtin_amdgcn_mfma_f32_16x16x32_bf16(    \
                        af[i_], bf[j_], acc[i_][j_], 0, 0, 0);                \
        }                                                                     \
    }

    STAGE(0, 0);
    STAGE(1, 1);                            // 16 loads in flight

    for (int kt = 0; kt < 14; ++kt) {
        int p = kt & 1;
        // retire tile kt's 8 loads; tile kt+1's 8 stay in flight
        asm volatile("s_waitcnt vmcnt(8)" ::: "memory");
        __builtin_amdgcn_s_barrier();       // all waves' quarters of tile kt in LDS
        __builtin_amdgcn_sched_barrier(0);
        COMPUTE(p);
        asm volatile("s_waitcnt lgkmcnt(0)" ::: "memory");  // reads of buf p done
        __builtin_amdgcn_sched_barrier(0);
        __builtin_amdgcn_s_barrier();       // all waves done reading buf p
        STAGE(p, kt + 2);                   // overwrite buf p with tile kt+2
    }
    // kt = 14
    asm volatile("s_waitcnt vmcnt(8)" ::: "memory");
    __builtin_amdgcn_s_barrier();
    __builtin_amdgcn_sched_barrier(0);
    COMPUTE(0);
    // kt = 15
    asm volatile("s_waitcnt vmcnt(0)" ::: "memory");
    __builtin_amdgcn_s_barrier();
    __builtin_amdgcn_sched_barrier(0);
    COMPUTE(1);
#undef STAGE
#undef COMPUTE

    __syncthreads();                        // before epilogue reuses SH as staging

    // ---------------- epilogue ----------------
    int m0 = mt * 128;
    int col0 = nt * 128 + wc * 64;          // wave's 64-col block = one head
    if (z == 2) {
        #pragma unroll
        for (int j = 0; j < 4; ++j) {
            int col = col0 + j * 16 + lm;
            float bsv = bias[col];
            int h = col >> 6, hd = col & 63;
            #pragma unroll
            for (int i = 0; i < 4; ++i) {
                int m = m0 + wr * 64 + i * 16 + lq * 4;
                int b_ = m >> 10, sr = m & 1023;
                union { float f; unsigned u; } p0, p1, p2, p3;
                p0.f = acc[i][j][0] + bsv; p1.f = acc[i][j][1] + bsv;
                p2.f = acc[i][j][2] + bsv; p3.f = acc[i][j][3] + bsv;
                uint2 pk;
                pk.x = __builtin_amdgcn_perm(p1.u + 0x8000u, p0.u + 0x8000u, 0x07060302u);
                pk.y = __builtin_amdgcn_perm(p3.u + 0x8000u, p2.u + 0x8000u, 0x07060302u);
                *reinterpret_cast<uint2*>(out + (((b_ * HH + h) * HDIM + hd) << 10) + sr) = pk;
            }
        }
    } else {
        unsigned short* S = SH + wave * 4864;   // 64*76 per wave, aliases K-loop bufs
        #pragma unroll
        for (int j = 0; j < 4; ++j) {
            float bsv = bias[col0 + j * 16 + lm];
            #pragma unroll
            for (int i = 0; i < 4; ++i) {
                #pragma unroll
                for (int r = 0; r < 4; ++r) {
                    union { float f; unsigned u; } cv; cv.f = acc[i][j][r] + bsv;
                    S[(i * 16 + lq * 4 + r) * 76 + j * 16 + lm] =
                        (unsigned short)((cv.u + 0x8000u) >> 16);
                }
            }
        }
        int h = col0 >> 6;
        int mrow = m0 + wr * 64;
        int b_ = mrow >> 10, sr0 = mrow & 1023;
        unsigned short* ob = out + ((size_t)((b_ * HH + h) << 10) + sr0) * HDIM;
        #pragma unroll
        for (int u = 0; u < 8; ++u) {
            int s = lane + u * 64;
            int row = s >> 3, c8 = s & 7;
            uint4 v = *reinterpret_cast<const uint4*>(&S[row * 76 + c8 * 8]);
            *reinterpret_cast<uint4*>(ob + row * HDIM + c8 * 8) = v;
        }
    }
}

// ================= Kernel 3: flash attention v7 (verified best) =================
// 256 q-rows/block (4 strips of 16 per wave, 64 apart), Kt=64, 16 iters.
// One kf/vf LDS read pair feeds FOUR strips' MFMAs. 512 blocks, 2 blocks/CU.
__global__ __launch_bounds__(256, 2) void attention(
    const unsigned short* __restrict__ q,     // [bh][s][hd]
    const unsigned short* __restrict__ k,     // [bh][s][hd]
    const unsigned short* __restrict__ vt,    // [bh][hd][s]
    const float* __restrict__ mask,
    float* __restrict__ out)
{
    __shared__ unsigned short Ks[2][64 * 64];   // [key][hd], swizzled chunks
    __shared__ unsigned short Vs[2][64 * 64];   // [hd][key], swizzled chunks
    __shared__ unsigned short Ps[4][16 * 64];   // per-wave P[q][key], swizzled

    int blk = blockIdx.x;
    int xcd = blk & 7, j = blk >> 3;            // j 0..63
    int bh = (xcd << 4) + (j >> 2);
    int qt = j & 3;                             // 0..3: 256 q-rows each
    int b = bh >> 4, h = bh & 15;

    int tid = threadIdx.x;
    int wave = tid >> 6, lane = tid & 63, lq = lane >> 4, lm = lane & 15;

    const unsigned short* qp = q + (size_t)bh * SS * HDIM;
    const unsigned short* kp = k + (size_t)bh * SS * HDIM;
    const unsigned short* vp = vt + (size_t)bh * HDIM * SS;
    const float* maskb = mask + b * SS;

    // Q fragments for 4 strips (B-operand: B[k=lq*8+j][n=lm])
    int qbase = qt * 256 + wave * 16 + lm;
    bf16x8 qa[4][2];
    #pragma unroll
    for (int s = 0; s < 4; ++s) {
        qa[s][0] = *reinterpret_cast<const bf16x8*>(qp + (qbase + s * 64) * HDIM + lq * 8);
        qa[s][1] = *reinterpret_cast<const bf16x8*>(qp + (qbase + s * 64) * HDIM + 32 + lq * 8);
    }

    float lsum[4] = {0.f, 0.f, 0.f, 0.f};
    f32x4 o[4][4] = {};                         // [strip][nb2]

    // staging: slot tid -> (row=tid>>3, s=tid&7); +256 -> row+32
    int row0 = tid >> 3, sg = tid & 7;
    int cg = (sg - row0) & 7;                   // chunk swizzle (c + row) & 7
    const unsigned short* gk = kp + row0 * 64 + cg * 8;
    const unsigned short* gv = vp + row0 * SS + cg * 8;

    int sl0 = ((lq + lm) & 7) * 8;              // Ks/Vs frag swizzled offsets
    int sl1 = ((lq + lm + 4) & 7) * 8;
    unsigned short* Pw = Ps[wave];
    int pwbase = lm * 64 + (lq & 1) * 4;        // P-write: chunk nb*2+(lq>>1)
    int prd0 = lm * 64 + sl0;                   // P-read chunk lq (ks=0)
    int prd1 = lm * 64 + sl1;                   // P-read chunk 4+lq (ks=1)

    async16(&Ks[0][tid * 8], gk);  async16(&Ks[0][(tid + 256) * 8], gk + 32 * 64);
    async16(&Vs[0][tid * 8], gv);  async16(&Vs[0][(tid + 256) * 8], gv + 32 * SS);
    gk += 64 * 64; gv += 64;

    for (int t = 0; t < 16; ++t) {
        int p = t & 1;
        __syncthreads();
        int kb0 = t * 64;

        // mask (L2-hot) BEFORE prefetch: its vmcnt wait tolerates the asyncs
        float4 mk[4];
        #pragma unroll
        for (int nb = 0; nb < 4; ++nb) {
            mk[nb] = *reinterpret_cast<const float4*>(maskb + kb0 + nb * 16 + lq * 4);
            #pragma unroll
            for (int r = 0; r < 4; ++r)
                reinterpret_cast<float*>(&mk[nb])[r] *= 1.44269504f;
        }
        if (t < 15) {
            async16(&Ks[p ^ 1][tid * 8], gk);  async16(&Ks[p ^ 1][(tid + 256) * 8], gk + 32 * 64);
            async16(&Vs[p ^ 1][tid * 8], gv);  async16(&Vs[p ^ 1][(tid + 256) * 8], gv + 32 * SS);
            gk += 64 * 64; gv += 64;
        }

        // 1. scores for ALL 4 strips off one Ks read pair per nb
        f32x4 c[4][4];                          // [strip][nb]
        #pragma unroll
        for (int nb = 0; nb < 4; ++nb) {
            bf16x8 kf0 = *reinterpret_cast<const bf16x8*>(&Ks[p][(nb * 16 + lm) * 64 + sl0]);
            bf16x8 kf1 = *reinterpret_cast<const bf16x8*>(&Ks[p][(nb * 16 + lm) * 64 + sl1]);
            #pragma unroll
            for (int s = 0; s < 4; ++s) {
                f32x4 z = {};
                z = __builtin_amdgcn_mfma_f32_16x16x32_bf16(kf0, qa[s][0], z, 0, 0, 0);
                z = __builtin_amdgcn_mfma_f32_16x16x32_bf16(kf1, qa[s][1], z, 0, 0, 0);
                c[s][nb] = z;
            }
        }

        // 2. per strip: exp + P-write + P-read (in-order DS reuse of Ps, x4)
        bf16x8 pa[4][2];
        #pragma unroll
        for (int s = 0; s < 4; ++s) {
            #pragma unroll
            for (int nb = 0; nb < 4; ++nb) {
                unsigned u[4];
                #pragma unroll
                for (int r = 0; r < 4; ++r) {
                    float e = exp2fast(fmaf(c[s][nb][r], 0.18033688f,
                                            reinterpret_cast<const float*>(&mk[nb])[r]));
                    union { float f; unsigned v; } cv; cv.f = e;
                    u[r] = cv.v;
                    union { unsigned v; float f; } tr; tr.v = cv.v & 0xffff0000u;
                    lsum[s] += tr.f;            // lsum of TRUNCATED p: exact cancel
                }
                uint2 pk;
                pk.x = __builtin_amdgcn_perm(u[1], u[0], 0x07060302u);
                pk.y = __builtin_amdgcn_perm(u[3], u[2], 0x07060302u);
                *reinterpret_cast<uint2*>(
                    &Pw[pwbase + (((nb * 2 + (lq >> 1)) + lm) & 7) * 8]) = pk;
            }
            pa[s][0] = *reinterpret_cast<const bf16x8*>(&Pw[prd0]);
            pa[s][1] = *reinterpret_cast<const bf16x8*>(&Pw[prd1]);
        }

        // 3. PV: each Vs read pair feeds all 4 strips
        #pragma unroll
        for (int nb2 = 0; nb2 < 4; ++nb2) {
            bf16x8 vf0 = *reinterpret_cast<const bf16x8*>(&Vs[p][(nb2 * 16 + lm) * 64 + sl0]);
            bf16x8 vf1 = *reinterpret_cast<const bf16x8*>(&Vs[p][(nb2 * 16 + lm) * 64 + sl1]);
            #pragma unroll
            for (int s = 0; s < 4; ++s) {
                o[s][nb2] = __builtin_amdgcn_mfma_f32_16x16x32_bf16(pa[s][0], vf0, o[s][nb2], 0, 0, 0);
                o[s][nb2] = __builtin_amdgcn_mfma_f32_16x16x32_bf16(pa[s][1], vf1, o[s][nb2], 0, 0, 0);
            }
        }
    }

    // reduce lsum (per qrow=lm, 4 lq-copies) and write all 4 strips
    float linv[4][4];
    #pragma unroll
    for (int s = 0; s < 4; ++s) {
        lsum[s] += __shfl_xor(lsum[s], 16, 64);
        lsum[s] += __shfl_xor(lsum[s], 32, 64);
        #pragma unroll
        for (int r = 0; r < 4; ++r)
            linv[s][r] = 1.0f / __shfl(lsum[s], lq * 4 + r, 64);
    }

    int srb = qt * 256 + wave * 16;
    #pragma unroll
    for (int s = 0; s < 4; ++s) {
        #pragma unroll
        for (int nb2 = 0; nb2 < 4; ++nb2) {
            #pragma unroll
            for (int r = 0; r < 4; ++r) {
                int sr = srb + s * 64 + lq * 4 + r;
                out[((size_t)(b * SS + sr)) * DD + h * HDIM + nb2 * 16 + lm] =
                    o[s][nb2][r] * linv[s][r];
            }
        }
    }
}

extern "C" void kernel_launch(void* const* d_in, const int* in_sizes, int n_in,
                              void* d_out, int out_size, void* d_ws, size_t ws_size,
                              hipStream_t stream) {
    const float* hs   = (const float*)d_in[0];
    const float* mask = (const float*)d_in[1];
    const float* Wq   = (const float*)d_in[2];
    const float* bq   = (const float*)d_in[3];
    const float* Wk   = (const float*)d_in[4];
    const float* bk   = (const float*)d_in[5];
    const float* Wv   = (const float*)d_in[6];
    const float* bv   = (const float*)d_in[7];
    float* out = (float*)d_out;

    char* ws = (char*)d_ws;
    // ws layout (bytes): Xb 16MB | Wt0/1/2 2MB each | q,k,vt 16MB each = 70MB
    unsigned short* XB  = (unsigned short*)(ws);
    unsigned short* WT0 = (unsigned short*)(ws + 16777216);
    unsigned short* WT1 = (unsigned short*)(ws + 18874368);
    unsigned short* WT2 = (unsigned short*)(ws + 20971520);
    unsigned short* qw  = (unsigned short*)(ws + 23068672);
    unsigned short* kw  = (unsigned short*)(ws + 39845888);
    unsigned short* vtw = (unsigned short*)(ws + 56623104);

    prep<<<4864, 256, 0, stream>>>(hs, XB, Wq, Wk, Wv, WT0, WT1, WT2);
    gemm_qkv<<<1536, 256, 0, stream>>>(XB, WT0, WT1, WT2,
                                       bq, bk, bv, qw, kw, vtw);
    attention<<<512, 256, 0, stream>>>(qw, kw, vtw, mask, out);
}